// Round 10
// baseline (308.670 us; speedup 1.0000x reference)
//
#include <hip/hip_runtime.h>
#include <cstdint>
#include <cstddef>

#define Bsz 8
#define Ssz 256
#define Msz 2048
#define SPLITK 16

typedef _Float16 f16x8 __attribute__((ext_vector_type(8)));
typedef float f32x16 __attribute__((ext_vector_type(16)));

// ---------------- one-time pack (+ counter zeroing) ----------------
// W1 [128][8192] f32  -> W1pk [512 kc][4 pb][64 lane][8] f16
// W2 [128][16384] f32 -> W2pk [1024][4][64][8] f16
// dep [2048][64] f32  -> dpk  [8 pc][2048 m][8] f16
// tok [2048][128] f32 -> tokT [128 t][2048 m] f16
__global__ __launch_bounds__(256) void k_pack(
    const float* __restrict__ W1, const float* __restrict__ W2,
    const float* __restrict__ dep, const float* __restrict__ tok,
    _Float16* __restrict__ W1pk, _Float16* __restrict__ W2pk,
    _Float16* __restrict__ dpk,  _Float16* __restrict__ tokT,
    unsigned* __restrict__ cnt)
{
  __shared__ float tile[32][33];
  const int bx = blockIdx.x, tid = threadIdx.x;
  if (bx == 0 && tid < 64) cnt[tid] = 0;   // poison-safe counter init each launch
  if (bx < 768) {
    const bool isW1 = bx < 256;
    const int idx = (isW1 ? bx : bx - 256) * 256 + tid;
    const int r  = idx & 31;
    const int pb = (idx >> 5) & 3;
    const int kc = idx >> 7;
    const float* src = (isW1 ? W1 : W2) + (size_t)(pb * 32 + r) * (isW1 ? 8192 : 16384) + kc * 16;
    const float4* s4 = (const float4*)src;
    float4 u0 = s4[0], u1 = s4[1], u2 = s4[2], u3 = s4[3];
    f16x8 lo = {(_Float16)u0.x,(_Float16)u0.y,(_Float16)u0.z,(_Float16)u0.w,
                (_Float16)u1.x,(_Float16)u1.y,(_Float16)u1.z,(_Float16)u1.w};
    f16x8 hi = {(_Float16)u2.x,(_Float16)u2.y,(_Float16)u2.z,(_Float16)u2.w,
                (_Float16)u3.x,(_Float16)u3.y,(_Float16)u3.z,(_Float16)u3.w};
    _Float16* dst = (isW1 ? W1pk : W2pk) + ((size_t)(kc * 4 + pb) * 64) * 8;
    *(f16x8*)(dst + (size_t)r * 8)        = lo;   // lanes 0-31: k 0..7
    *(f16x8*)(dst + (size_t)(32 + r) * 8) = hi;   // lanes 32-63: k 8..15
  } else if (bx < 832) {
    const int idx = (bx - 768) * 256 + tid;
    const int m = idx & 2047, pc = idx >> 11;
    const float4* s4 = (const float4*)(dep + (size_t)m * 64 + pc * 8);
    float4 u0 = s4[0], u1 = s4[1];
    f16x8 v = {(_Float16)u0.x,(_Float16)u0.y,(_Float16)u0.z,(_Float16)u0.w,
               (_Float16)u1.x,(_Float16)u1.y,(_Float16)u1.z,(_Float16)u1.w};
    *(f16x8*)(dpk + ((size_t)pc * Msz + m) * 8) = v;
  } else {
    const int q = bx - 832;
    const int mt = q >> 2, tt = q & 3;
    const int tx = tid & 31, ty = tid >> 5;
    for (int yy = ty; yy < 32; yy += 8)
      tile[yy][tx] = tok[(size_t)(mt * 32 + yy) * 128 + tt * 32 + tx];
    __syncthreads();
    for (int yy = ty; yy < 32; yy += 8)
      tokT[(size_t)(tt * 32 + yy) * Msz + mt * 32 + tx] = (_Float16)tile[tx][yy];
  }
}

// ---------------- fused phase: MFMA GEMM partial + last-block reduce+tanh ----------------
// Round-5 proven structure (64m x 128n, 4 waves, 2 accs) + hoisted tokT (static unroll).
// mfma_f32_32x32x16_f16: A row=lane&31, k=(lane>>5)*8+j; B col same; D col=lane&31,
// row=(reg&3)+8*(reg>>2)+4*(lane>>5).
template<int LGDV, int KC, bool TO_HPK>
__global__ __launch_bounds__(256, 2) void k_phase(
    const _Float16* __restrict__ Apk,   // [DV/8][Msz][8]
    const _Float16* __restrict__ Wpk,   // [Ktot/16][4][64][8]
    const _Float16* __restrict__ tokT,  // [128][Msz]
    const float*    __restrict__ bias,  // [128]
    float* __restrict__ part,           // [SPLITK][Msz][128]
    unsigned* __restrict__ cnt,         // [32] per-mb arrival counters
    _Float16* __restrict__ hpk,         // phase1 out [16][2048][8]
    float* __restrict__ spc)            // phase2 out [2048][128]
{
  constexpr int DV  = 1 << LGDV;
  constexpr int NT  = KC >> LGDV;      // 8
  constexpr int NKS = DV >> 4;         // 4 (phase1) or 8 (phase2)

  const int tid  = threadIdx.x;
  const int lane = tid & 63;
  const int wo   = tid >> 6;           // n-quarter
  const int l31  = lane & 31;
  const int lg   = lane >> 5;
  const int id   = blockIdx.x;
  const int sk   = (id & 7) + 8 * (id >> 8);   // same-XCD blocks share sk pair -> W L2-resident
  const int mb   = (id >> 3) & 31;
  const int m0   = mb * 64;
  const int mrow0 = m0 + l31;

  // hoist A fragments (invariant across t)
  f16x8 a0[NKS], a1[NKS];
  #pragma unroll
  for (int ks = 0; ks < NKS; ++ks) {
    const _Float16* ap = Apk + ((size_t)(ks * 2 + lg) * Msz + mrow0) * 8;
    a0[ks] = *(const f16x8*)(ap);
    a1[ks] = *(const f16x8*)(ap + 32 * 8);
  }
  // hoist tokT (breaks per-t-step dependent-load chain); static indexing via full unroll
  const int t0 = sk * NT;
  _Float16 tra[NT], trb[NT];
  #pragma unroll
  for (int i = 0; i < NT; ++i) {
    tra[i] = tokT[(size_t)(t0 + i) * Msz + mrow0];
    trb[i] = tokT[(size_t)(t0 + i) * Msz + mrow0 + 32];
  }

  f32x16 acc0 = {}, acc1 = {};
  const int kc0 = sk * (KC >> 4);
  #pragma unroll
  for (int tg = 0; tg < NT; ++tg) {
    const _Float16 ta = tra[tg], tb = trb[tg];
    const f16x8 tav = {ta,ta,ta,ta,ta,ta,ta,ta};
    const f16x8 tbv = {tb,tb,tb,tb,tb,tb,tb,tb};
    #pragma unroll
    for (int ks = 0; ks < NKS; ++ks) {
      const f16x8 b = *(const f16x8*)(Wpk + (((size_t)(kc0 + tg * NKS + ks) * 4 + wo) * 64 + lane) * 8);
      const f16x8 af0 = tav * a0[ks];
      const f16x8 af1 = tbv * a1[ks];
      acc0 = __builtin_amdgcn_mfma_f32_32x32x16_f16(af0, b, acc0, 0, 0, 0);
      acc1 = __builtin_amdgcn_mfma_f32_32x32x16_f16(af1, b, acc1, 0, 0, 0);
    }
  }

  // partial store
  float* dst = part + (size_t)sk * (Msz * 128);
  const int ocol = wo * 32 + l31;
  #pragma unroll
  for (int r = 0; r < 16; ++r) {
    const int mrow = m0 + (r & 3) + 8 * (r >> 2) + 4 * lg;
    dst[(size_t)mrow * 128 + ocol]        = acc0[r];
    dst[(size_t)(mrow + 32) * 128 + ocol] = acc1[r];
  }

  // ---- last-block split-K reduce + bias + tanh ----
  __threadfence();                       // release partials (device scope)
  __syncthreads();                       // order all threads' fences before arrival
  __shared__ int lastFlag;
  if (tid == 0) {
    unsigned old = atomicAdd(&cnt[mb], 1u);
    lastFlag = (old == SPLITK - 1);
    if (old == SPLITK - 1) cnt[mb] = 0;  // self-reset for next phase / replay
  }
  __syncthreads();
  if (!lastFlag) return;
  __threadfence();                       // acquire other blocks' partials

  const int ml  = tid & 63;
  const int pg  = tid >> 6;              // 0..3
  const int row = m0 + ml;
  #pragma unroll
  for (int q = 0; q < 4; ++q) {
    const int pc8 = pg * 4 + q;          // p>>3, 16 total
    const int p0  = pc8 * 8;
    float s[8];
    {
      float4 b0 = *(const float4*)(bias + p0);
      float4 b1 = *(const float4*)(bias + p0 + 4);
      s[0]=b0.x; s[1]=b0.y; s[2]=b0.z; s[3]=b0.w;
      s[4]=b1.x; s[5]=b1.y; s[6]=b1.z; s[7]=b1.w;
    }
    #pragma unroll
    for (int k2 = 0; k2 < SPLITK; ++k2) {
      const float* pp = part + (size_t)k2 * (Msz * 128) + (size_t)row * 128 + p0;
      float4 v0 = *(const float4*)pp;
      float4 v1 = *(const float4*)(pp + 4);
      s[0]+=v0.x; s[1]+=v0.y; s[2]+=v0.z; s[3]+=v0.w;
      s[4]+=v1.x; s[5]+=v1.y; s[6]+=v1.z; s[7]+=v1.w;
    }
    #pragma unroll
    for (int e = 0; e < 8; ++e) s[e] = tanhf(s[e]);
    if (TO_HPK) {
      f16x8 h8 = {(_Float16)s[0],(_Float16)s[1],(_Float16)s[2],(_Float16)s[3],
                  (_Float16)s[4],(_Float16)s[5],(_Float16)s[6],(_Float16)s[7]};
      *(f16x8*)(hpk + ((size_t)pc8 * Msz + row) * 8) = h8;
    } else {
      float* op = spc + (size_t)row * 128 + p0;
      *(float4*)op       = make_float4(s[0], s[1], s[2], s[3]);
      *(float4*)(op + 4) = make_float4(s[4], s[5], s[6], s[7]);
    }
  }
}

// ---------------- finalize: gather over j with head[b,j]==i ----------------
__global__ __launch_bounds__(128) void k_finalize(
    const float* __restrict__ special,  // [Msz][128]
    const int*   __restrict__ heads,    // [Bsz][Ssz]
    const float* __restrict__ wred,     // [Ssz]
    const float* __restrict__ bred,     // [1]
    const float* __restrict__ bcomp,    // [128]
    float* __restrict__ out)            // [Bsz][Ssz][128]
{
  int b = blockIdx.x >> 8;
  int i = blockIdx.x & 255;
  int t = threadIdx.x;
  __shared__ float wr_s[Ssz];
  __shared__ int   hd_s[Ssz];
  wr_s[t]       = wred[t];
  wr_s[t + 128] = wred[t + 128];
  hd_s[t]       = heads[b * Ssz + t];
  hd_s[t + 128] = heads[b * Ssz + t + 128];
  __syncthreads();

  const float base  = tanhf(bcomp[t]);
  const float bred0 = bred[0];
  float swr = 0.f, accv = 0.f;
  #pragma unroll 1
  for (int j = 0; j < Ssz; j++) {
    swr += wr_s[j];
    if (hd_s[j] == i)
      accv += wr_s[j] * (special[((size_t)b * Ssz + j) * 128 + t] - base);
  }
  out[((size_t)b * Ssz + i) * 128 + t] = base * swr + bred0 + accv;
}

extern "C" void kernel_launch(void* const* d_in, const int* in_sizes, int n_in,
                              void* d_out, int out_size, void* d_ws, size_t ws_size,
                              hipStream_t stream) {
  const float* tok   = (const float*)d_in[0];
  const float* dep   = (const float*)d_in[1];
  const int*   hds   = (const int*)  d_in[2];
  const float* Wdep  = (const float*)d_in[3];
  const float* bdep  = (const float*)d_in[4];
  const float* Wcomp = (const float*)d_in[5];
  const float* bcomp = (const float*)d_in[6];
  const float* Wred  = (const float*)d_in[7];
  const float* bred  = (const float*)d_in[8];
  float* out = (float*)d_out;

  char* ws = (char*)d_ws;
  _Float16* W1pk = (_Float16*)(ws);                 // 2 MB
  _Float16* W2pk = (_Float16*)(ws + (2u  << 20));   // 4 MB
  _Float16* dpk  = (_Float16*)(ws + (6u  << 20));   // 256 KB
  _Float16* tokT = (_Float16*)(ws + (7u  << 20));   // 512 KB
  _Float16* hpk  = (_Float16*)(ws + (8u  << 20));   // 512 KB
  float*    part = (float*)   (ws + (9u  << 20));   // 16 MB
  float*    spc  = (float*)   (ws + (25u << 20));   // 1 MB
  unsigned* cnt  = (unsigned*)(ws + (26u << 20));   // 256 B

  k_pack<<<1088, 256, 0, stream>>>(Wdep, Wcomp, dep, tok, W1pk, W2pk, dpk, tokT, cnt);

  // Phase 1: K=8192 (t*64+d), KC=512. 32 mb x 16 sk = 512 blocks.
  k_phase<6, 512, true ><<<512, 256, 0, stream>>>(dpk, W1pk, tokT, bdep, part, cnt, hpk, nullptr);
  // Phase 2: K=16384 (t*128+p), KC=1024.
  k_phase<7, 1024, false><<<512, 256, 0, stream>>>(hpk, W2pk, tokT, bcomp, part, cnt, nullptr, spc);

  k_finalize<<<dim3(Bsz * Ssz), 128, 0, stream>>>(spc, hds, Wred, bred, bcomp, out);
}

// Round 11
// 67.823 us; speedup vs baseline: 4.5511x; 4.5511x over previous
//
#include <hip/hip_runtime.h>
#include <cstdint>
#include <cstddef>

#define Bsz 8
#define Ssz 256
#define Msz 2048
#define SPLITK 16

typedef _Float16 f16x8 __attribute__((ext_vector_type(8)));
typedef _Float16 f16x4 __attribute__((ext_vector_type(4)));
typedef float f32x16 __attribute__((ext_vector_type(16)));

// ---------------- one-time pack ----------------
// W1 [128][8192] f32  -> W1pk [512 kc][4 pb][64 lane][8] f16
// W2 [128][16384] f32 -> W2pk [1024][4][64][8] f16
// dep [2048][64] f32  -> dpk  [8 pc][2048 m][8] f16
// tok [2048][128] f32 -> tokT [128 t][2048 m] f16
__global__ __launch_bounds__(256) void k_pack(
    const float* __restrict__ W1, const float* __restrict__ W2,
    const float* __restrict__ dep, const float* __restrict__ tok,
    _Float16* __restrict__ W1pk, _Float16* __restrict__ W2pk,
    _Float16* __restrict__ dpk,  _Float16* __restrict__ tokT)
{
  __shared__ float tile[32][33];
  const int bx = blockIdx.x, tid = threadIdx.x;
  if (bx < 768) {
    const bool isW1 = bx < 256;
    const int idx = (isW1 ? bx : bx - 256) * 256 + tid;
    const int r  = idx & 31;
    const int pb = (idx >> 5) & 3;
    const int kc = idx >> 7;
    const float* src = (isW1 ? W1 : W2) + (size_t)(pb * 32 + r) * (isW1 ? 8192 : 16384) + kc * 16;
    const float4* s4 = (const float4*)src;
    float4 u0 = s4[0], u1 = s4[1], u2 = s4[2], u3 = s4[3];
    f16x8 lo = {(_Float16)u0.x,(_Float16)u0.y,(_Float16)u0.z,(_Float16)u0.w,
                (_Float16)u1.x,(_Float16)u1.y,(_Float16)u1.z,(_Float16)u1.w};
    f16x8 hi = {(_Float16)u2.x,(_Float16)u2.y,(_Float16)u2.z,(_Float16)u2.w,
                (_Float16)u3.x,(_Float16)u3.y,(_Float16)u3.z,(_Float16)u3.w};
    _Float16* dst = (isW1 ? W1pk : W2pk) + ((size_t)(kc * 4 + pb) * 64) * 8;
    *(f16x8*)(dst + (size_t)r * 8)        = lo;   // lanes 0-31: k 0..7
    *(f16x8*)(dst + (size_t)(32 + r) * 8) = hi;   // lanes 32-63: k 8..15
  } else if (bx < 832) {
    const int idx = (bx - 768) * 256 + tid;
    const int m = idx & 2047, pc = idx >> 11;
    const float4* s4 = (const float4*)(dep + (size_t)m * 64 + pc * 8);
    float4 u0 = s4[0], u1 = s4[1];
    f16x8 v = {(_Float16)u0.x,(_Float16)u0.y,(_Float16)u0.z,(_Float16)u0.w,
               (_Float16)u1.x,(_Float16)u1.y,(_Float16)u1.z,(_Float16)u1.w};
    *(f16x8*)(dpk + ((size_t)pc * Msz + m) * 8) = v;
  } else {
    const int q = bx - 832;
    const int mt = q >> 2, tt = q & 3;
    const int tx = tid & 31, ty = tid >> 5;
    for (int yy = ty; yy < 32; yy += 8)
      tile[yy][tx] = tok[(size_t)(mt * 32 + yy) * 128 + tt * 32 + tx];
    __syncthreads();
    for (int yy = ty; yy < 32; yy += 8)
      tokT[(size_t)(tt * 32 + yy) * Msz + mt * 32 + tx] = (_Float16)tile[tx][yy];
  }
}

// ---------------- MFMA GEMM: 64m x 128n block, 4 waves, A+tokT hoisted ----------------
// Round-5 proven structure; no fences, no atomics. 512 blocks = 2/CU.
// mfma_f32_32x32x16_f16: A row=lane&31, k=(lane>>5)*8+j; B col same; D col=lane&31,
// row=(reg&3)+8*(reg>>2)+4*(lane>>5).
template<int LGDV, int KC>
__global__ __launch_bounds__(256, 2) void k_gemm(
    const _Float16* __restrict__ Apk,   // [DV/8][Msz][8]
    const _Float16* __restrict__ Wpk,   // [Ktot/16][4][64][8]
    const _Float16* __restrict__ tokT,  // [128][Msz]
    float* __restrict__ part)           // [SPLITK][Msz][128]
{
  constexpr int DV  = 1 << LGDV;
  constexpr int NT  = KC >> LGDV;      // 8
  constexpr int NKS = DV >> 4;         // 4 (phase1) or 8 (phase2)

  const int tid  = threadIdx.x;
  const int lane = tid & 63;
  const int wo   = tid >> 6;           // n-quarter
  const int l31  = lane & 31;
  const int lg   = lane >> 5;
  const int id   = blockIdx.x;
  const int sk   = (id & 7) + 8 * (id >> 8);   // same-XCD blocks share sk -> W slice L2-resident
  const int mb   = (id >> 3) & 31;
  const int m0   = mb * 64;
  const int mrow0 = m0 + l31;

  // hoist A fragments (invariant across t)
  f16x8 a0[NKS], a1[NKS];
  #pragma unroll
  for (int ks = 0; ks < NKS; ++ks) {
    const _Float16* ap = Apk + ((size_t)(ks * 2 + lg) * Msz + mrow0) * 8;
    a0[ks] = *(const f16x8*)(ap);
    a1[ks] = *(const f16x8*)(ap + 32 * 8);
  }
  // hoist tokT for all NT t's (kills per-t-step dependent-load stall); static indexing
  const int t0 = sk * NT;
  _Float16 tra[NT], trb[NT];
  #pragma unroll
  for (int i = 0; i < NT; ++i) {
    tra[i] = tokT[(size_t)(t0 + i) * Msz + mrow0];
    trb[i] = tokT[(size_t)(t0 + i) * Msz + mrow0 + 32];
  }

  f32x16 acc0 = {}, acc1 = {};
  const int kc0 = sk * (KC >> 4);
  #pragma unroll
  for (int tg = 0; tg < NT; ++tg) {
    const _Float16 ta = tra[tg], tb = trb[tg];
    const f16x8 tav = {ta,ta,ta,ta,ta,ta,ta,ta};
    const f16x8 tbv = {tb,tb,tb,tb,tb,tb,tb,tb};
    #pragma unroll
    for (int ks = 0; ks < NKS; ++ks) {
      const f16x8 b = *(const f16x8*)(Wpk + (((size_t)(kc0 + tg * NKS + ks) * 4 + wo) * 64 + lane) * 8);
      const f16x8 af0 = tav * a0[ks];
      const f16x8 af1 = tbv * a1[ks];
      acc0 = __builtin_amdgcn_mfma_f32_32x32x16_f16(af0, b, acc0, 0, 0, 0);
      acc1 = __builtin_amdgcn_mfma_f32_32x32x16_f16(af1, b, acc1, 0, 0, 0);
    }
  }

  float* dst = part + (size_t)sk * (Msz * 128);
  const int ocol = wo * 32 + l31;
  #pragma unroll
  for (int r = 0; r < 16; ++r) {
    const int mrow = m0 + (r & 3) + 8 * (r >> 2) + 4 * lg;
    dst[(size_t)mrow * 128 + ocol]        = acc0[r];
    dst[(size_t)(mrow + 32) * 128 + ocol] = acc1[r];
  }
}

// ---------------- split-K reduce + bias + tanh (float4) ----------------
template<bool TO_HPK>
__global__ __launch_bounds__(256) void k_red(
    const float* __restrict__ part, const float* __restrict__ bias,
    _Float16* __restrict__ hpk, float* __restrict__ spc)
{
  const int u  = blockIdx.x * 256 + threadIdx.x;   // 65536 units x 4 elems
  const int e4 = u * 4;
  const int m = e4 >> 7, p = e4 & 127;
  float4 s = *(const float4*)(bias + p);
  #pragma unroll
  for (int sk = 0; sk < SPLITK; sk++) {
    float4 v = *(const float4*)(part + (size_t)sk * (Msz * 128) + e4);
    s.x += v.x; s.y += v.y; s.z += v.z; s.w += v.w;
  }
  s.x = tanhf(s.x); s.y = tanhf(s.y); s.z = tanhf(s.z); s.w = tanhf(s.w);
  if (TO_HPK) {
    f16x4 h4 = {(_Float16)s.x, (_Float16)s.y, (_Float16)s.z, (_Float16)s.w};
    *(f16x4*)(hpk + ((size_t)(p >> 3) * Msz + m) * 8 + (p & 7)) = h4;
  } else {
    *(float4*)(spc + e4) = s;
  }
}

// ---------------- finalize: gather over j with head[b,j]==i ----------------
__global__ __launch_bounds__(128) void k_finalize(
    const float* __restrict__ special,  // [Msz][128]
    const int*   __restrict__ heads,    // [Bsz][Ssz]
    const float* __restrict__ wred,     // [Ssz]
    const float* __restrict__ bred,     // [1]
    const float* __restrict__ bcomp,    // [128]
    float* __restrict__ out)            // [Bsz][Ssz][128]
{
  int b = blockIdx.x >> 8;
  int i = blockIdx.x & 255;
  int t = threadIdx.x;
  __shared__ float wr_s[Ssz];
  __shared__ int   hd_s[Ssz];
  wr_s[t]       = wred[t];
  wr_s[t + 128] = wred[t + 128];
  hd_s[t]       = heads[b * Ssz + t];
  hd_s[t + 128] = heads[b * Ssz + t + 128];
  __syncthreads();

  const float base  = tanhf(bcomp[t]);
  const float bred0 = bred[0];
  float swr = 0.f, accv = 0.f;
  #pragma unroll 1
  for (int j = 0; j < Ssz; j++) {
    swr += wr_s[j];
    if (hd_s[j] == i)
      accv += wr_s[j] * (special[((size_t)b * Ssz + j) * 128 + t] - base);
  }
  out[((size_t)b * Ssz + i) * 128 + t] = base * swr + bred0 + accv;
}

extern "C" void kernel_launch(void* const* d_in, const int* in_sizes, int n_in,
                              void* d_out, int out_size, void* d_ws, size_t ws_size,
                              hipStream_t stream) {
  const float* tok   = (const float*)d_in[0];
  const float* dep   = (const float*)d_in[1];
  const int*   hds   = (const int*)  d_in[2];
  const float* Wdep  = (const float*)d_in[3];
  const float* bdep  = (const float*)d_in[4];
  const float* Wcomp = (const float*)d_in[5];
  const float* bcomp = (const float*)d_in[6];
  const float* Wred  = (const float*)d_in[7];
  const float* bred  = (const float*)d_in[8];
  float* out = (float*)d_out;

  char* ws = (char*)d_ws;
  _Float16* W1pk = (_Float16*)(ws);                 // 2 MB
  _Float16* W2pk = (_Float16*)(ws + (2u  << 20));   // 4 MB
  _Float16* dpk  = (_Float16*)(ws + (6u  << 20));   // 256 KB
  _Float16* tokT = (_Float16*)(ws + (7u  << 20));   // 512 KB
  _Float16* hpk  = (_Float16*)(ws + (8u  << 20));   // 512 KB
  float*    part = (float*)   (ws + (9u  << 20));   // 16 MB
  float*    spc  = (float*)   (ws + (25u << 20));   // 1 MB

  k_pack<<<1088, 256, 0, stream>>>(Wdep, Wcomp, dep, tok, W1pk, W2pk, dpk, tokT);

  // Phase 1: K=8192 (t*64+d), KC=512. 32 mb x 16 sk = 512 blocks.
  k_gemm<6, 512><<<512, 256, 0, stream>>>(dpk, W1pk, tokT, part);
  k_red<true><<<256, 256, 0, stream>>>(part, bdep, hpk, nullptr);

  // Phase 2: K=16384 (t*128+p), KC=1024.
  k_gemm<7, 1024><<<512, 256, 0, stream>>>(hpk, W2pk, tokT, part);
  k_red<false><<<256, 256, 0, stream>>>(part, bcomp, nullptr, spc);

  k_finalize<<<dim3(Bsz * Ssz), 128, 0, stream>>>(spc, hds, Wred, bred, bcomp, out);
}